// Round 1
// baseline (1581.472 us; speedup 1.0000x reference)
//
#include <hip/hip_runtime.h>

#define H_ 16
#define L_ 4096
#define D_ 64
#define S_ 72            // LDS row stride in 2B elements (144 B = 16 B multiple, breaks pow2 conflicts)
#define NKT 64           // number of 64-wide K tiles

typedef __attribute__((ext_vector_type(4))) float    f32x4;
typedef __attribute__((ext_vector_type(8))) short    s16x8;
typedef __attribute__((ext_vector_type(4))) short    s16x4;
typedef __attribute__((ext_vector_type(8))) _Float16 h16x8;
typedef __attribute__((ext_vector_type(4))) _Float16 h16x4;

__device__ __forceinline__ short f2bf(float x) {      // fp32 -> bf16 bits, RNE
    unsigned u = __float_as_uint(x);
    u = (u + 0x7fffu + ((u >> 16) & 1u)) >> 16;
    return (short)u;
}
__device__ __forceinline__ float bf2f(short b) {
    return __uint_as_float(((unsigned)(unsigned short)b) << 16);
}

// ---- prep: VT[h][d][n] = (fp16) V[h][n][d] ----
__global__ __launch_bounds__(256) void vt_kernel(const float* __restrict__ v,
                                                 _Float16* __restrict__ vt) {
    __shared__ float tile[64][65];
    const int h = blockIdx.y, t = blockIdx.x, tid = threadIdx.x;
    const int c = tid & 15, r = tid >> 4;
    const float* src = v + ((size_t)(h * L_ + t * 64)) * D_;
    for (int i = 0; i < 4; ++i) {
        int n = r + 16 * i;
        f32x4 x = *(const f32x4*)(src + (size_t)n * D_ + c * 4);
        tile[n][c * 4 + 0] = x.x;
        tile[n][c * 4 + 1] = x.y;
        tile[n][c * 4 + 2] = x.z;
        tile[n][c * 4 + 3] = x.w;
    }
    __syncthreads();
    _Float16* dst = vt + (size_t)h * D_ * L_ + t * 64;
    for (int j = 0; j < 4; ++j) {
        int d = r + 16 * j;
        int n0 = c * 4;
        h16x4 y;
        y.x = (_Float16)tile[n0 + 0][d];
        y.y = (_Float16)tile[n0 + 1][d];
        y.z = (_Float16)tile[n0 + 2][d];
        y.w = (_Float16)tile[n0 + 3][d];
        *(h16x4*)(dst + (size_t)d * L_ + n0) = y;
    }
}

// stage a 64x64 fp32 tile as bf16 hi/lo split into LDS (coalesced float4 reads)
__device__ __forceinline__ void stage_split(const float* __restrict__ src,
                                            short* __restrict__ hiB,
                                            short* __restrict__ loB,
                                            int tid, float scale) {
    const int c = (tid & 15) * 4, r0 = tid >> 4;
    for (int i = 0; i < 4; ++i) {
        int r = r0 + 16 * i;
        f32x4 x = *(const f32x4*)(src + (size_t)r * D_ + c);
        x.x *= scale; x.y *= scale; x.z *= scale; x.w *= scale;
        s16x4 hi, lo;
        short h0 = f2bf(x.x); hi.x = h0; lo.x = f2bf(x.x - bf2f(h0));
        short h1 = f2bf(x.y); hi.y = h1; lo.y = f2bf(x.y - bf2f(h1));
        short h2 = f2bf(x.z); hi.z = h2; lo.z = f2bf(x.z - bf2f(h2));
        short h3 = f2bf(x.w); hi.w = h3; lo.w = f2bf(x.w - bf2f(h3));
        *(s16x4*)(hiB + r * S_ + c) = hi;
        *(s16x4*)(loB + r * S_ + c) = lo;
    }
}

// one block = one head x 64 query rows. wave w owns key-band [16w,16w+16) for S^T
// and O-rows [16w,16w+16) for PV.
__global__ __launch_bounds__(256, 2) void attn_kernel(
    const float* __restrict__ q, const float* __restrict__ k,
    const _Float16* __restrict__ vt,
    float* __restrict__ out, float* __restrict__ score)
{
    __shared__ __align__(16) short    Qh[64 * S_], Ql[64 * S_], Kh[64 * S_], Kl[64 * S_];
    __shared__ __align__(16) _Float16 Ps[64 * S_], Vs[64 * S_];
    __shared__ float redM[4][64], redL[4][64];

    const int h = blockIdx.y, qb = blockIdx.x, tid = threadIdx.x;
    const int w = tid >> 6, lane = tid & 63, lrow = lane & 15, lgrp = lane >> 4;

    // Q tile: scale by 1/sqrt(64)=0.125 (exact pow2) then bf16 hi/lo split
    stage_split(q + ((size_t)(h * L_ + qb * 64)) * D_, Qh, Ql, tid, 0.125f);
    __syncthreads();

    // hoist all Q (B-operand) fragments: B[k=d][col=m] -> lane reads Q[16mt+lrow][lgrp*8+32ks..+8]
    s16x8 bQh[4][2], bQl[4][2];
    for (int mt = 0; mt < 4; ++mt)
        for (int ks = 0; ks < 2; ++ks) {
            int off = (16 * mt + lrow) * S_ + lgrp * 8 + 32 * ks;
            bQh[mt][ks] = *(s16x8*)(Qh + off);
            bQl[mt][ks] = *(s16x8*)(Ql + off);
        }

    float M[4], Ls[4];
    for (int mt = 0; mt < 4; ++mt) { M[mt] = -1e30f; Ls[mt] = 0.f; }

    const float* kbase = k + (size_t)h * L_ * D_;

    // ---------- phase 1: online row stats over all 4096 keys ----------
    for (int kt = 0; kt < NKT; ++kt) {
        __syncthreads();
        stage_split(kbase + (size_t)kt * 64 * D_, Kh, Kl, tid, 1.0f);
        __syncthreads();
        s16x8 aKh[2], aKl[2];
        for (int ks = 0; ks < 2; ++ks) {
            int off = (16 * w + lrow) * S_ + lgrp * 8 + 32 * ks;
            aKh[ks] = *(s16x8*)(Kh + off);
            aKl[ks] = *(s16x8*)(Kl + off);
        }
        for (int mt = 0; mt < 4; ++mt) {
            f32x4 acc = {0.f, 0.f, 0.f, 0.f};
            for (int ks = 0; ks < 2; ++ks) {
                acc = __builtin_amdgcn_mfma_f32_16x16x32_bf16(aKh[ks], bQh[mt][ks], acc, 0, 0, 0);
                acc = __builtin_amdgcn_mfma_f32_16x16x32_bf16(aKh[ks], bQl[mt][ks], acc, 0, 0, 0);
                acc = __builtin_amdgcn_mfma_f32_16x16x32_bf16(aKl[ks], bQh[mt][ks], acc, 0, 0, 0);
            }
            // S^T C-frag: col(lane&15)=query m, row(lgrp*4+reg)=key n -> reduce over regs + lanes^16,^32
            float tm = fmaxf(fmaxf(acc.x, acc.y), fmaxf(acc.z, acc.w));
            tm = fmaxf(tm, __shfl_xor(tm, 16));
            tm = fmaxf(tm, __shfl_xor(tm, 32));
            float nM = fmaxf(M[mt], tm);
            float s = __expf(acc.x - nM) + __expf(acc.y - nM)
                    + __expf(acc.z - nM) + __expf(acc.w - nM);
            s += __shfl_xor(s, 16);
            s += __shfl_xor(s, 32);
            Ls[mt] = Ls[mt] * __expf(M[mt] - nM) + s;
            M[mt] = nM;
        }
    }

    // combine the 4 waves' partial stats (each wave covered n%64 in [16w,16w+16))
    if (lgrp == 0)
        for (int mt = 0; mt < 4; ++mt) {
            redM[w][16 * mt + lrow] = M[mt];
            redL[w][16 * mt + lrow] = Ls[mt];
        }
    __syncthreads();
    float Mf[4], Li[4];
    for (int mt = 0; mt < 4; ++mt) {
        int m = 16 * mt + lrow;
        float m0 = redM[0][m], m1 = redM[1][m], m2 = redM[2][m], m3 = redM[3][m];
        float mm = fmaxf(fmaxf(m0, m1), fmaxf(m2, m3));
        float ls = redL[0][m] * __expf(m0 - mm) + redL[1][m] * __expf(m1 - mm)
                 + redL[2][m] * __expf(m2 - mm) + redL[3][m] * __expf(m3 - mm);
        Mf[mt] = mm; Li[mt] = 1.f / ls;
    }

    // ---------- phase 2: recompute S^T, emit P, accumulate O = P·V ----------
    f32x4 accO[4];
    for (int dt = 0; dt < 4; ++dt) accO[dt] = (f32x4){0.f, 0.f, 0.f, 0.f};

    float* scbase = score + ((size_t)(h * L_ + qb * 64)) * L_;
    const _Float16* vtb = vt + (size_t)h * D_ * L_;

    for (int kt = 0; kt < NKT; ++kt) {
        __syncthreads();
        stage_split(kbase + (size_t)kt * 64 * D_, Kh, Kl, tid, 1.0f);
        {   // stage VT tile (fp16, already transposed): Vs[d][n]
            const int c8 = (tid & 7) * 8, r8 = tid >> 3;
            for (int i = 0; i < 2; ++i) {
                int d = r8 + 32 * i;
                h16x8 x = *(const h16x8*)(vtb + (size_t)d * L_ + kt * 64 + c8);
                *(h16x8*)(Vs + d * S_ + c8) = x;
            }
        }
        __syncthreads();
        s16x8 aKh[2], aKl[2];
        for (int ks = 0; ks < 2; ++ks) {
            int off = (16 * w + lrow) * S_ + lgrp * 8 + 32 * ks;
            aKh[ks] = *(s16x8*)(Kh + off);
            aKl[ks] = *(s16x8*)(Kl + off);
        }
        for (int mt = 0; mt < 4; ++mt) {
            f32x4 acc = {0.f, 0.f, 0.f, 0.f};
            for (int ks = 0; ks < 2; ++ks) {
                acc = __builtin_amdgcn_mfma_f32_16x16x32_bf16(aKh[ks], bQh[mt][ks], acc, 0, 0, 0);
                acc = __builtin_amdgcn_mfma_f32_16x16x32_bf16(aKh[ks], bQl[mt][ks], acc, 0, 0, 0);
                acc = __builtin_amdgcn_mfma_f32_16x16x32_bf16(aKl[ks], bQh[mt][ks], acc, 0, 0, 0);
            }
            int m = 16 * mt + lrow;
            f32x4 p;
            p.x = __expf(acc.x - Mf[mt]) * Li[mt];
            p.y = __expf(acc.y - Mf[mt]) * Li[mt];
            p.z = __expf(acc.z - Mf[mt]) * Li[mt];
            p.w = __expf(acc.w - Mf[mt]) * Li[mt];
            // 4 consecutive n per lane -> one float4 store; 16 lanes cover a 64B row segment
            *(f32x4*)(scbase + (size_t)m * L_ + kt * 64 + 16 * w + lgrp * 4) = p;
            h16x4 ph;
            ph.x = (_Float16)p.x; ph.y = (_Float16)p.y;
            ph.z = (_Float16)p.z; ph.w = (_Float16)p.w;
            *(h16x4*)(Ps + m * S_ + 16 * w + lgrp * 4) = ph;   // b64, 2-way bank alias (free)
        }
        __syncthreads();
        // O[m][d] += P[m][n] * V[n][d]; A-frag from Ps rows [16w..), B-frag from Vs (=V^T) rows d
        for (int ks = 0; ks < 2; ++ks) {
            s16x8 aPs = *(s16x8*)((short*)Ps + (16 * w + lrow) * S_ + lgrp * 8 + 32 * ks);
            h16x8 aP = __builtin_bit_cast(h16x8, aPs);
            for (int dt = 0; dt < 4; ++dt) {
                h16x8 bV = *(h16x8*)(Vs + (16 * dt + lrow) * S_ + lgrp * 8 + 32 * ks);
                accO[dt] = __builtin_amdgcn_mfma_f32_16x16x32_f16(aP, bV, accO[dt], 0, 0, 0);
            }
        }
    }

    // O C-frag: d = 16*dt + lrow, m = 16*w + lgrp*4 + reg
    float* obase = out + ((size_t)(h * L_ + qb * 64)) * D_;
    for (int dt = 0; dt < 4; ++dt)
        for (int r2 = 0; r2 < 4; ++r2) {
            int m = 16 * w + lgrp * 4 + r2;
            obase[(size_t)m * D_ + 16 * dt + lrow] = accO[dt][r2];
        }
}

extern "C" void kernel_launch(void* const* d_in, const int* in_sizes, int n_in,
                              void* d_out, int out_size, void* d_ws, size_t ws_size,
                              hipStream_t stream) {
    const float* q = (const float*)d_in[0];
    const float* kk = (const float*)d_in[1];
    const float* v = (const float*)d_in[2];
    float* out = (float*)d_out;
    float* score = out + (size_t)H_ * L_ * D_;   // tuple order: (out, score)
    _Float16* vt = (_Float16*)d_ws;              // 16*64*4096*2B = 8 MB scratch

    vt_kernel<<<dim3(L_ / 64, H_), 256, 0, stream>>>(v, vt);
    attn_kernel<<<dim3(L_ / 64, H_), 256, 0, stream>>>(q, kk, vt, out, score);
}